// Round 4
// baseline (28.775 us; speedup 1.0000x reference)
//
#include <hip/hip_runtime.h>

// Sinkhorn OT loss via prefix-LSE scans. N=2048 frames, A=64 osc, B=513 bins,
// eps=0.01 -> beta = 100*log2(e)*15.625 per bin step (base-2 log domain).
// ILP-2: each 128-thread block owns 2 frames; wave0 = L/P scans, wave1 = R/S
// scans, each wave processing both frames per phase (independent chains
// interleave in the pipeline, halving barrier cost per frame-iteration).
// Cross-lane scan levels 1,2,4,8 use DPP row_shr/shl with NEGF fill
// (select-free); levels 16,32 use shfl with precomputed "dead" decay regs.
// Final pi*cost pass is fused into iteration 5 (moment-augmented B + C).

#define NN 2048
#define NEGF (-1.0e30f)
#define BETA 2254.2110013890053f          // 100*log2(e)*15.625
#define B8   18033.688011112042f          // 8*BETA
#define INVB (1.0f/2254.2110013890053f)
#define SCALE 15.625f

static __device__ __forceinline__ float EXP2(float x) { return __builtin_amdgcn_exp2f(x); }
static __device__ __forceinline__ float LOG2(float x) { return __builtin_amdgcn_logf(x); }

static __device__ __forceinline__ float lse1(float x, float y) {
    float mx = fmaxf(x, y);
    float mn = fminf(x, y);
    return mx + LOG2(1.0f + EXP2(mn - mx));
}
static __device__ __forceinline__ float wave_sum(float v) {
#pragma unroll
    for (int o = 32; o > 0; o >>= 1) v += __shfl_xor(v, o);
    return v;
}
// shift-up/down across lanes; D<=8 via DPP (invalid lanes -> fill), else shfl.
template<int D> static __device__ __forceinline__ float shup(float x) {
    if constexpr (D <= 8)
        return __int_as_float(__builtin_amdgcn_update_dpp(
            __float_as_int(NEGF), __float_as_int(x), 0x110 + D, 0xf, 0xf, false));
    else return __shfl_up(x, D);
}
template<int D> static __device__ __forceinline__ float shdn(float x) {
    if constexpr (D <= 8)
        return __int_as_float(__builtin_amdgcn_update_dpp(
            __float_as_int(NEGF), __float_as_int(x), 0x100 + D, 0xf, 0xf, false));
    else return __shfl_down(x, D);
}
template<int D> static __device__ __forceinline__ float shup0(float x) {
    if constexpr (D <= 8)
        return __int_as_float(__builtin_amdgcn_update_dpp(
            0, __float_as_int(x), 0x110 + D, 0xf, 0xf, false));
    else return __shfl_up(x, D);
}
template<int D> static __device__ __forceinline__ float shdn0(float x) {
    if constexpr (D <= 8)
        return __int_as_float(__builtin_amdgcn_update_dpp(
            0, __float_as_int(x), 0x100 + D, 0xf, 0xf, false));
    else return __shfl_down(x, D);
}

struct FrameLds {
    float Vs[576];                 // pidx-padded V over bins 0..511
    float PL[576];                 // local L-prefix per bin (pidx-padded)
    float PR[584];                 // local R-suffix per bin incl 512 (pidx(512)=576)
    float TL[65];                  // TL[0]=NEGF; TL[1+j] = cross L-prefix ref bin 8j+7
    float TR[66];                  // TR[j] = cross R-suffix ref bin 8j; [64],[65]=NEGF
    float tp[66];                  // sorted osc t + sentinels
    float smu[64];                 // sorted Mu2
    float OPa[66], OSa[66], OMa[66], OSMa[66];
    float part[2];
};

__global__ __launch_bounds__(128) void sink2_kernel(
    const float* __restrict__ freqs, const float* __restrict__ amps,
    const float* __restrict__ spec, float* __restrict__ ws)
{
    const int nb  = blockIdx.x;          // 0..1023 (2 frames each)
    const int tid = threadIdx.x;
    const int w   = tid >> 6, l = tid & 63;

    __shared__ __align__(16) float tsr[2][64];
    __shared__ FrameLds L[2];

    // ---- per-wave raw frame (wave w preps frame w) ----
    float traw = freqs[(2*nb + w)*64 + l] * (1.0f/15.625f);   // bin units, [0,512)
    float ta   = amps [(2*nb + w)*64 + l];
    ta = fminf(fmaxf(ta, 0.0f), 1e9f) + 1e-9f;
    float Sa   = wave_sum(ta);
    float Mraw = LOG2(ta) - LOG2(Sa);
    tsr[w][l] = traw;

    // ---- spec: both waves, both frames; thread owns 4 bins/frame ----
    float tv[2][4], s512v[2] = {0.0f, 0.0f};
#pragma unroll
    for (int f = 0; f < 2; ++f) {
        const float* sp = spec + (2*nb + f)*513;
        float part = 0.0f;
#pragma unroll
        for (int c = 0; c < 4; ++c) {
            float x = sp[w*256 + c*64 + l];
            x = fminf(fmaxf(x, 0.0f), 1e9f) + 1e-9f;
            tv[f][c] = x; part += x;
        }
        if (w == 1 && l == 63) {
            float x = fminf(fmaxf(sp[512], 0.0f), 1e9f) + 1e-9f;
            s512v[f] = x; part += x;
        }
        part = wave_sum(part);
        if (l == 0) L[f].part[w] = part;
    }
    if (tid == 0) {
#pragma unroll
        for (int f = 0; f < 2; ++f) {
            L[f].tp[0] = 0.0f;  L[f].tp[65] = 20000.0f;
            L[f].TL[0] = NEGF;  L[f].TR[64] = NEGF; L[f].TR[65] = NEGF;
            L[f].OPa[0] = NEGF; L[f].OMa[0] = 0.0f;
            L[f].OSa[65] = NEGF; L[f].OSMa[65] = 0.0f;
        }
    }
    int vix[4];
#pragma unroll
    for (int c = 0; c < 4; ++c) {
        int bin = w*256 + c*64 + l;
        vix[c] = bin + (bin >> 3);
        L[0].Vs[vix[c]] = 0.0f; L[1].Vs[vix[c]] = 0.0f;
    }
    __syncthreads();   // B1: tsr/part/sentinels/Vs visible

    float Nu4[2][4], Nu512v[2] = {0.0f, 0.0f}, V512v[2] = {NEGF, NEGF};
#pragma unroll
    for (int f = 0; f < 2; ++f) {
        float lsn = LOG2(L[f].part[0] + L[f].part[1]);
#pragma unroll
        for (int c = 0; c < 4; ++c) Nu4[f][c] = LOG2(tv[f][c]) - lsn;
        if (w == 1 && l == 63) { Nu512v[f] = LOG2(s512v[f]) - lsn; V512v[f] = 0.0f; }
    }

    // ---- rank sort (wave w sorts frame w); no dependent levels ----
    {
        int r = 0;
        const float4* t4 = (const float4*)tsr[w];
#pragma unroll
        for (int q = 0; q < 16; ++q) {
            float4 tt = t4[q]; int j = 4*q;
            r += (tt.x < traw) || (tt.x == traw && (j+0) < l);
            r += (tt.y < traw) || (tt.y == traw && (j+1) < l);
            r += (tt.z < traw) || (tt.z == traw && (j+2) < l);
            r += (tt.w < traw) || (tt.w == traw && (j+3) < l);
        }
        L[w].tp[1 + r] = traw;
        L[w].smu[r]    = Mraw;
    }
    __syncthreads();   // B2: sorted arrays visible

    // ---- sorted state + per-level decay registers ----
    float t2[2], Mu2[2], bgU[2][6], bgD[2][6];
#pragma unroll
    for (int f = 0; f < 2; ++f) {
        t2[f]  = L[f].tp[1 + l];
        Mu2[f] = L[f].smu[l];
#pragma unroll
        for (int k = 0; k < 6; ++k) {
            int d = 1 << k;
            float tu = __shfl_up(t2[f], d);
            float td = __shfl_down(t2[f], d);
            float bu = BETA*(t2[f] - tu);
            float bd = BETA*(td - t2[f]);
            if (k >= 4) {                      // shfl levels: kill clamped lanes
                if (l < d)      bu = 3.0e12f;
                if (l + d > 63) bd = 3.0e12f;
            }
            bgU[f][k] = bu; bgD[f][k] = bd;
        }
    }

    // ---- per-owned-bin osc split (iteration-invariant) ----
    int   jl4[2][4];
    float bdL4[2][4], bdR4[2][4], bdL512[2] = {0.0f, 0.0f};
#pragma unroll
    for (int f = 0; f < 2; ++f) {
#pragma unroll
        for (int c = 0; c < 4; ++c) {
            float bf = (float)(w*256 + c*64 + l);
            int lo = 0, hi = 65;
#pragma unroll
            for (int s = 0; s < 7; ++s) {
                int mid = (lo + hi) >> 1;
                bool le = (L[f].tp[mid] <= bf);
                lo = le ? mid : lo;
                hi = le ? hi : mid;
            }
            jl4[f][c] = lo;
            bdL4[f][c] = BETA*(bf - L[f].tp[lo]);
            bdR4[f][c] = BETA*(L[f].tp[lo + 1] - bf);
        }
        if (w == 1 && l == 63) bdL512[f] = BETA*(512.0f - L[f].tp[64]);
    }

    float U2[2] = {0.0f, 0.0f};

    auto phaseA = [&]() {
#pragma unroll
        for (int f = 0; f < 2; ++f) {
            float v8[8];
#pragma unroll
            for (int i = 0; i < 8; ++i) v8[i] = L[f].Vs[9*l + i];
            if (w == 0) {
                float acc = v8[0]; L[f].PL[9*l] = acc;
#pragma unroll
                for (int i = 1; i < 8; ++i) { acc = lse1(acc - BETA, v8[i]); L[f].PL[9*l + i] = acc; }
                acc = lse1(shup<1>(acc) - B8*1.0f,  acc);
                acc = lse1(shup<2>(acc) - B8*2.0f,  acc);
                acc = lse1(shup<4>(acc) - B8*4.0f,  acc);
                acc = lse1(shup<8>(acc) - B8*8.0f,  acc);
                acc = lse1(shup<16>(acc) - B8*16.0f, acc);
                acc = lse1(shup<32>(acc) - B8*32.0f, acc);
                L[f].TL[1 + l] = acc;
            } else {
                float acc = lse1(V512v[f] - BETA, v8[7]);   // NEGF except lane 63
                L[f].PR[9*l + 7] = acc;
#pragma unroll
                for (int i = 6; i >= 0; --i) { acc = lse1(acc - BETA, v8[i]); L[f].PR[9*l + i] = acc; }
                if (l == 63) L[f].PR[576] = V512v[f];
                acc = lse1(shdn<1>(acc) - B8*1.0f,  acc);
                acc = lse1(shdn<2>(acc) - B8*2.0f,  acc);
                acc = lse1(shdn<4>(acc) - B8*4.0f,  acc);
                acc = lse1(shdn<8>(acc) - B8*8.0f,  acc);
                acc = lse1(shdn<16>(acc) - B8*16.0f, acc);
                acc = lse1(shdn<32>(acc) - B8*32.0f, acc);
                L[f].TR[l] = acc;
            }
        }
    };
    auto queryU = [&]() {
#pragma unroll
        for (int f = 0; f < 2; ++f) {
            float t = t2[f];
            int b0 = (int)t;                       // t < 512
            int blk = b0 >> 3;
            float a1 = L[f].TL[blk]               - BETA*(t - (float)(8*blk - 1));
            float a2 = L[f].PL[b0 + (b0 >> 3)]    - BETA*(t - (float)b0);
            int b1 = b0 + 1, bkR = b1 >> 3;
            float a3 = L[f].TR[bkR + 1]           - BETA*((float)(8*(bkR + 1)) - t);
            float a4 = L[f].PR[b1 + (b1 >> 3)]    - BETA*((float)b1 - t);
            U2[f] = Mu2[f] - lse1(lse1(a1, a2), lse1(a3, a4));
        }
    };

#pragma unroll 1
    for (int it = 0; it < 4; ++it) {
        phaseA();
        __syncthreads();
        queryU();
        // phase B: osc scans (select-free)
#pragma unroll
        for (int f = 0; f < 2; ++f) {
            if (w == 0) {
                float P = U2[f];
                P = lse1(shup<1>(P)  - bgU[f][0], P);
                P = lse1(shup<2>(P)  - bgU[f][1], P);
                P = lse1(shup<4>(P)  - bgU[f][2], P);
                P = lse1(shup<8>(P)  - bgU[f][3], P);
                P = lse1(shup<16>(P) - bgU[f][4], P);
                P = lse1(shup<32>(P) - bgU[f][5], P);
                L[f].OPa[1 + l] = P;
            } else {
                float S = U2[f];
                S = lse1(shdn<1>(S)  - bgD[f][0], S);
                S = lse1(shdn<2>(S)  - bgD[f][1], S);
                S = lse1(shdn<4>(S)  - bgD[f][2], S);
                S = lse1(shdn<8>(S)  - bgD[f][3], S);
                S = lse1(shdn<16>(S) - bgD[f][4], S);
                S = lse1(shdn<32>(S) - bgD[f][5], S);
                L[f].OSa[1 + l] = S;
            }
        }
        __syncthreads();
        // phase C: V update on owned bins
#pragma unroll
        for (int f = 0; f < 2; ++f) {
#pragma unroll
            for (int c = 0; c < 4; ++c) {
                int iL = jl4[f][c], iR = iL + 1;
                float EL = L[f].OPa[iL] - bdL4[f][c];
                float ER = L[f].OSa[iR] - bdR4[f][c];
                L[f].Vs[vix[c]] = Nu4[f][c] - lse1(EL, ER);
            }
            if (w == 1 && l == 63)
                V512v[f] = Nu512v[f] - (L[f].OPa[64] - bdL512[f]);
        }
        __syncthreads();
    }

    // ======== iteration 5: fused with final pi*cost pass ========
    phaseA();
    __syncthreads();
    queryU();
    // phase B with moments (F-recursion identical to P/S scan)
#pragma unroll
    for (int f = 0; f < 2; ++f) {
        if (w == 0) {
            float F = U2[f], M = 0.0f;
#define MSTEP_U(D, K) { float o = shup<D>(F); float om = shup0<D>(M);            \
        float xo = o - bgU[f][K]; float Lc = lse1(xo, F);                        \
        float wa = EXP2(xo - Lc), wb = EXP2(F - Lc);                             \
        M = fmaf(wa, om + bgU[f][K]*INVB, wb*M); F = Lc; }
            MSTEP_U(1,0) MSTEP_U(2,1) MSTEP_U(4,2) MSTEP_U(8,3) MSTEP_U(16,4) MSTEP_U(32,5)
#undef MSTEP_U
            L[f].OPa[1 + l] = F; L[f].OMa[1 + l] = M;
        } else {
            float F = U2[f], M = 0.0f;
#define MSTEP_D(D, K) { float o = shdn<D>(F); float om = shdn0<D>(M);            \
        float xo = o - bgD[f][K]; float Lc = lse1(xo, F);                        \
        float wa = EXP2(xo - Lc), wb = EXP2(F - Lc);                             \
        M = fmaf(wa, om + bgD[f][K]*INVB, wb*M); F = Lc; }
            MSTEP_D(1,0) MSTEP_D(2,1) MSTEP_D(4,2) MSTEP_D(8,3) MSTEP_D(16,4) MSTEP_D(32,5)
#undef MSTEP_D
            L[f].OSa[1 + l] = F; L[f].OSMa[1 + l] = M;
        }
    }
    __syncthreads();
    // final phase C: V update folded into pi*cost contributions
    float acc2[2] = {0.0f, 0.0f};
#pragma unroll
    for (int f = 0; f < 2; ++f) {
#pragma unroll
        for (int c = 0; c < 4; ++c) {
            int iL = jl4[f][c], iR = iL + 1;
            float EL = L[f].OPa[iL] - bdL4[f][c];
            float ER = L[f].OSa[iR] - bdR4[f][c];
            float Vn = Nu4[f][c] - lse1(EL, ER);
            float dL = bdL4[f][c]*INVB, dR = bdR4[f][c]*INVB;
            acc2[f] += EXP2(Vn + EL)*(L[f].OMa[iL] + dL)
                     + EXP2(Vn + ER)*(L[f].OSMa[iR] + dR);
        }
        if (w == 1 && l == 63) {
            float EL = L[f].OPa[64] - bdL512[f];
            float Vn = Nu512v[f] - EL;
            acc2[f] += EXP2(Vn + EL)*(L[f].OMa[64] + bdL512[f]*INVB);
        }
    }
#pragma unroll
    for (int f = 0; f < 2; ++f) {
        float s = wave_sum(acc2[f]);
        if (l == 0) L[f].part[w] = s;
    }
    __syncthreads();
    if (tid == 0) {
        ws[2*nb + 0] = (L[0].part[0] + L[0].part[1]) * SCALE;
        ws[2*nb + 1] = (L[1].part[0] + L[1].part[1]) * SCALE;
    }
}

// Deterministic second-stage reduction (no atomics -> bit-stable across replays).
__global__ __launch_bounds__(256) void reduce_kernel(
    const float* __restrict__ ws, float* __restrict__ out)
{
    __shared__ float sm[4];
    int tid = threadIdx.x;
    float s = 0.0f;
    for (int i = tid; i < NN; i += 256) s += ws[i];
    s = wave_sum(s);
    if ((tid & 63) == 0) sm[tid >> 6] = s;
    __syncthreads();
    if (tid == 0) out[0] = (sm[0] + sm[1] + sm[2] + sm[3]) * (1.0f / 2048.0f);
}

extern "C" void kernel_launch(void* const* d_in, const int* in_sizes, int n_in,
                              void* d_out, int out_size, void* d_ws, size_t ws_size,
                              hipStream_t stream) {
    const float* freqs = (const float*)d_in[0];  // (2048,64)
    const float* amps  = (const float*)d_in[1];  // (2048,64)
    const float* spec  = (const float*)d_in[2];  // (2048,513)
    float* ws = (float*)d_ws;                    // 2048*4 B scratch

    sink2_kernel<<<NN/2, 128, 0, stream>>>(freqs, amps, spec, ws);
    reduce_kernel<<<1, 256, 0, stream>>>(ws, (float*)d_out);
}

// Round 5
// 22.539 us; speedup vs baseline: 1.2766x; 1.2766x over previous
//
#include <hip/hip_runtime.h>

// Sinkhorn OT loss, one 64-lane wave per frame, ZERO barriers.
// N=2048 frames, A=64 osc, B=513 bins, eps=0.01 -> beta=100*log2(e)*15.625.
// All cross-lane dataflow is in-wave (DPP/shfl/ds_bpermute); LDS only holds
// the sorted-t table and per-iteration local bin-prefixes for the U query.
// Iter 1 u-update is closed-form (V==0 => bin-scan == 0). V lives in regs.
// Final iteration fuses the moment-augmented scans + pi*cost (R4-validated).

#define NN 2048
#define NEGF (-1.0e30f)
#define DEAD 3.0e12f
#define BETA 2254.2110013890053f           // 100*log2(e)*15.625
#define B8   18033.688011112042f           // 8*BETA
#define INVB 4.4361353928294959e-4f        // 1/BETA
#define SCALE 15.625f

static __device__ __forceinline__ float EXP2(float x){ return __builtin_amdgcn_exp2f(x); }
static __device__ __forceinline__ float LOG2(float x){ return __builtin_amdgcn_logf(x); }
static __device__ __forceinline__ float lse1(float x, float y){
    float mx = fmaxf(x, y);
    return mx + LOG2(1.0f + EXP2(-fabsf(x - y)));   // fabs/neg fold to modifiers
}
static __device__ __forceinline__ float wave_sum(float v){
#pragma unroll
    for (int o = 32; o > 0; o >>= 1) v += __shfl_xor(v, o);
    return v;
}
// lane shift up/down: D<=8 via DPP with NEGF fill (select-free); 16/32 shfl
// (clamped lanes self-kill: uniform B8 decay or DEAD-folded gap regs).
template<int D> static __device__ __forceinline__ float shup(float x){
    if constexpr (D <= 8)
        return __int_as_float(__builtin_amdgcn_update_dpp(
            __float_as_int(NEGF), __float_as_int(x), 0x110 + D, 0xf, 0xf, false));
    else return __shfl_up(x, D);
}
template<int D> static __device__ __forceinline__ float shdn(float x){
    if constexpr (D <= 8)
        return __int_as_float(__builtin_amdgcn_update_dpp(
            __float_as_int(NEGF), __float_as_int(x), 0x100 + D, 0xf, 0xf, false));
    else return __shfl_down(x, D);
}
template<int D> static __device__ __forceinline__ float shup0(float x){
    if constexpr (D <= 8)
        return __int_as_float(__builtin_amdgcn_update_dpp(
            0, __float_as_int(x), 0x110 + D, 0xf, 0xf, false));
    else return __shfl_up(x, D);
}
template<int D> static __device__ __forceinline__ float shdn0(float x){
    if constexpr (D <= 8)
        return __int_as_float(__builtin_amdgcn_update_dpp(
            0, __float_as_int(x), 0x100 + D, 0xf, 0xf, false));
    else return __shfl_down(x, D);
}
static __device__ __forceinline__ float bperm(int a4, float v){
    return __int_as_float(__builtin_amdgcn_ds_bpermute(a4, __float_as_int(v)));
}
// padded bin index: 8-float lane block + 4 pad -> 48B stride, b128-aligned,
// conflict-free-optimal stores
static __device__ __forceinline__ int PIDX(int b){ return b + ((b >> 3) << 2); }

__global__ __launch_bounds__(64) void sink1_kernel(
    const float* __restrict__ freqs, const float* __restrict__ amps,
    const float* __restrict__ spec, float* __restrict__ ws)
{
    const int n = blockIdx.x, l = threadIdx.x;
    __shared__ __align__(16) float tsr[64];
    __shared__ float tp[66];
    __shared__ float smu[64];
    __shared__ __align__(16) float PLl[768];    // PIDX-padded local L-prefix
    __shared__ __align__(16) float PRl[769];    // PIDX-padded local R-suffix (incl bin 512)

    // ---- oscillator inputs ----
    float traw = freqs[n*64 + l] * (1.0f/15.625f);   // bin units, [0,512)
    float av   = amps [n*64 + l];
    av = fminf(fmaxf(av, 0.0f), 1e9f) + 1e-9f;
    float Sa   = wave_sum(av);
    float Mraw = LOG2(av) - LOG2(Sa);
    tsr[l] = traw;
    if (l == 0) { tp[0] = 0.0f; tp[65] = 20000.0f; }

    // ---- spec -> Nu (lane owns bins 8l..8l+7; lane63 also bin 512) ----
    const float* sp = spec + n*513;
    float sv[8], part = 0.0f;
#pragma unroll
    for (int i = 0; i < 8; ++i) {
        float x = sp[8*l + i];
        x = fminf(fmaxf(x, 0.0f), 1e9f) + 1e-9f;
        sv[i] = x; part += x;
    }
    float s512 = 0.0f;
    if (l == 63) { s512 = fminf(fmaxf(sp[512], 0.0f), 1e9f) + 1e-9f; part += s512; }
    float lsn = LOG2(wave_sum(part));
    float Nu8[8];
#pragma unroll
    for (int i = 0; i < 8; ++i) Nu8[i] = LOG2(sv[i]) - lsn;
    float Nu512 = (l == 63) ? (LOG2(s512) - lsn) : NEGF;

    // ---- rank sort (no dependent levels); lane becomes sorted osc index ----
    {
        int r = 0;
        const float4* t4 = (const float4*)tsr;
#pragma unroll
        for (int q = 0; q < 16; ++q) {
            float4 tt = t4[q]; int j = 4*q;
            r += (tt.x < traw) || (tt.x == traw && (j+0) < l);
            r += (tt.y < traw) || (tt.y == traw && (j+1) < l);
            r += (tt.z < traw) || (tt.z == traw && (j+2) < l);
            r += (tt.w < traw) || (tt.w == traw && (j+3) < l);
        }
        tp[1 + r] = traw;
        smu[r]    = Mraw;
    }
    float t  = tp[1 + l];
    float Mu = smu[l];

    // ---- per-level osc-scan decay regs (select-free) ----
    float bgU[6], bgD[6];
#pragma unroll
    for (int k = 0; k < 6; ++k) {
        int d = 1 << k;
        float tu = __shfl_up(t, d), td = __shfl_down(t, d);
        float bu = BETA*(t - tu), bd = BETA*(td - t);
        if (k >= 4) { if (l < d) bu = DEAD; if (l + d > 63) bd = DEAD; }
        bgU[k] = bu; bgD[k] = bd;
    }

    // ---- per-osc U-query statics ----
    int b0 = (int)t; if (b0 > 511) b0 = 511;
    float fr  = t - (float)b0;
    float bfr = BETA*fr, bnf = BETA*(1.0f - fr);
    int blk = b0 >> 3;
    int qa1 = (blk - 1) << 2;
    float qo1 = (blk == 0) ? DEAD : BETA*(t - (float)(8*blk - 1));
    int b1 = b0 + 1, bkR = b1 >> 3;
    int qa3 = (bkR + 1) << 2;
    float qo3 = (bkR + 1 > 63) ? DEAD : BETA*((float)(8*(bkR + 1)) - t);
    int pb0 = PIDX(b0), pb1 = PIDX(b1);

    // ---- per-owned-bin statics (binary search over sorted tp, once) ----
    int aL[8], aR[8]; float dl[8], dr[8];
#pragma unroll
    for (int i = 0; i < 8; ++i) {
        float bf = (float)(8*l + i);
        int lo = 0, hi = 65;
#pragma unroll
        for (int s = 0; s < 7; ++s) {
            int mid = (lo + hi) >> 1;
            bool le = (tp[mid] <= bf);
            lo = le ? mid : lo; hi = le ? hi : mid;
        }
        aL[i] = (lo - 1) << 2;                        // P-reg lane (junk killed if lo==0)
        dl[i] = (lo == 0)  ? DEAD : BETA*(bf - tp[lo]);
        aR[i] = lo << 2;                              // S-reg lane for osc lo+1
        dr[i] = (lo == 64) ? DEAD : BETA*(tp[lo + 1] - bf);
    }
    float dl512 = BETA*(512.0f - tp[64]);

    // ---- iter-1 u-update: closed form (V == 0) ----
    float U = Mu - lse1(-bfr, -bnf);

#pragma unroll 1
    for (int it = 0; it < 4; ++it) {
        // B: osc-axis scans of U (P up, S down) — pure registers
        float P = U;
        P = lse1(shup<1>(P)  - bgU[0], P);
        P = lse1(shup<2>(P)  - bgU[1], P);
        P = lse1(shup<4>(P)  - bgU[2], P);
        P = lse1(shup<8>(P)  - bgU[3], P);
        P = lse1(shup<16>(P) - bgU[4], P);
        P = lse1(shup<32>(P) - bgU[5], P);
        float S = U;
        S = lse1(shdn<1>(S)  - bgD[0], S);
        S = lse1(shdn<2>(S)  - bgD[1], S);
        S = lse1(shdn<4>(S)  - bgD[2], S);
        S = lse1(shdn<8>(S)  - bgD[3], S);
        S = lse1(shdn<16>(S) - bgD[4], S);
        S = lse1(shdn<32>(S) - bgD[5], S);
        // C: V on owned bins, straight into registers (bperm gathers)
        float v8[8];
#pragma unroll
        for (int i = 0; i < 8; ++i) {
            float EL = bperm(aL[i], P) - dl[i];
            float ER = bperm(aR[i], S) - dr[i];
            v8[i] = Nu8[i] - lse1(EL, ER);
        }
        float V512 = Nu512 - (bperm(63 << 2, P) - dl512);   // meaningful on lane63
        // A-L: intra-lane prefix + cross-lane (uniform B8 decay self-kills clamps)
        float pl[8];
        float acc = v8[0]; pl[0] = acc;
#pragma unroll
        for (int i = 1; i < 8; ++i) { acc = lse1(acc - BETA, v8[i]); pl[i] = acc; }
        float TL = acc;
        TL = lse1(shup<1>(TL)  - B8*1.0f,  TL);
        TL = lse1(shup<2>(TL)  - B8*2.0f,  TL);
        TL = lse1(shup<4>(TL)  - B8*4.0f,  TL);
        TL = lse1(shup<8>(TL)  - B8*8.0f,  TL);
        TL = lse1(shup<16>(TL) - B8*16.0f, TL);
        TL = lse1(shup<32>(TL) - B8*32.0f, TL);
        // A-R
        float seedR = (l == 63) ? V512 : NEGF;
        float prv[8];
        float racc = lse1(seedR - BETA, v8[7]); prv[7] = racc;
#pragma unroll
        for (int i = 6; i >= 0; --i) { racc = lse1(racc - BETA, v8[i]); prv[i] = racc; }
        float TR = racc;
        TR = lse1(shdn<1>(TR)  - B8*1.0f,  TR);
        TR = lse1(shdn<2>(TR)  - B8*2.0f,  TR);
        TR = lse1(shdn<4>(TR)  - B8*4.0f,  TR);
        TR = lse1(shdn<8>(TR)  - B8*8.0f,  TR);
        TR = lse1(shdn<16>(TR) - B8*16.0f, TR);
        TR = lse1(shdn<32>(TR) - B8*32.0f, TR);
        // store local prefixes for the O(1) U query (padded, b128-aligned)
        *(float4*)&PLl[12*l]     = make_float4(pl[0], pl[1], pl[2], pl[3]);
        *(float4*)&PLl[12*l + 4] = make_float4(pl[4], pl[5], pl[6], pl[7]);
        *(float4*)&PRl[12*l]     = make_float4(prv[0], prv[1], prv[2], prv[3]);
        *(float4*)&PRl[12*l + 4] = make_float4(prv[4], prv[5], prv[6], prv[7]);
        if (l == 63) PRl[768] = V512;                 // PIDX(512)
        // Q: u-update (in-wave LDS RAW, ordered by lgkmcnt — no barrier)
        float a1 = bperm(qa1, TL) - qo1;
        float a2 = PLl[pb0] - bfr;
        float a3 = bperm(qa3, TR) - qo3;
        float a4 = PRl[pb1] - bnf;
        U = Mu - lse1(lse1(a1, a2), lse1(a3, a4));
    }

    // ---- final: moment-augmented scans of U5 + fused pi*cost ----
    float FL = U, ML = 0.0f, FR = U, MR = 0.0f;
#define MU_(D,K) { float o = shup<D>(FL); float om = shup0<D>(ML);            \
    float xo = o - bgU[K]; float Lc = lse1(xo, FL);                           \
    ML = fmaf(EXP2(xo - Lc), fmaf(bgU[K], INVB, om), EXP2(FL - Lc)*ML); FL = Lc; }
    MU_(1,0) MU_(2,1) MU_(4,2) MU_(8,3) MU_(16,4) MU_(32,5)
#undef MU_
#define MD_(D,K) { float o = shdn<D>(FR); float om = shdn0<D>(MR);            \
    float xo = o - bgD[K]; float Lc = lse1(xo, FR);                           \
    MR = fmaf(EXP2(xo - Lc), fmaf(bgD[K], INVB, om), EXP2(FR - Lc)*MR); FR = Lc; }
    MD_(1,0) MD_(2,1) MD_(4,2) MD_(8,3) MD_(16,4) MD_(32,5)
#undef MD_

    float acc = 0.0f;
#pragma unroll
    for (int i = 0; i < 8; ++i) {
        float EL = bperm(aL[i], FL) - dl[i];
        float ER = bperm(aR[i], FR) - dr[i];
        float Vn = Nu8[i] - lse1(EL, ER);
        float mL = bperm(aL[i], ML);
        float mR = bperm(aR[i], MR);
        acc += EXP2(Vn + EL) * fmaf(dl[i], INVB, mL)
             + EXP2(Vn + ER) * fmaf(dr[i], INVB, mR);
    }
    float ml512 = bperm(63 << 2, ML);                 // hoisted out of the if
    if (l == 63) acc += EXP2(Nu512) * fmaf(dl512, INVB, ml512);

    acc = wave_sum(acc) * SCALE;
    if (l == 0) ws[n] = acc;
}

// Deterministic second-stage reduction (no atomics -> bit-stable across replays).
__global__ __launch_bounds__(256) void reduce_kernel(
    const float* __restrict__ ws, float* __restrict__ out)
{
    __shared__ float sm[4];
    int tid = threadIdx.x;
    const float4* w4 = (const float4*)ws;
    float4 a = w4[tid], b = w4[tid + 256];
    float s = (a.x + a.y + a.z + a.w) + (b.x + b.y + b.z + b.w);
    s = wave_sum(s);
    if ((tid & 63) == 0) sm[tid >> 6] = s;
    __syncthreads();
    if (tid == 0) out[0] = (sm[0] + sm[1] + sm[2] + sm[3]) * (1.0f / 2048.0f);
}

extern "C" void kernel_launch(void* const* d_in, const int* in_sizes, int n_in,
                              void* d_out, int out_size, void* d_ws, size_t ws_size,
                              hipStream_t stream) {
    const float* freqs = (const float*)d_in[0];  // (2048,64)
    const float* amps  = (const float*)d_in[1];  // (2048,64)
    const float* spec  = (const float*)d_in[2];  // (2048,513)
    float* ws = (float*)d_ws;                    // 2048*4 B scratch

    sink1_kernel<<<NN, 64, 0, stream>>>(freqs, amps, spec, ws);
    reduce_kernel<<<1, 256, 0, stream>>>(ws, (float*)d_out);
}